// Round 3
// baseline (2151.151 us; speedup 1.0000x reference)
//
#include <hip/hip_runtime.h>
#include <cstdint>

typedef unsigned int u32;
typedef unsigned short u16;
typedef short bf16x8 __attribute__((ext_vector_type(8)));
typedef float f32x4 __attribute__((ext_vector_type(4)));

#define Bq 512
#define Tq 100
#define NST 200
#define NLAT 30
#define NEMB 1024
#define NACT 6

// packed weight tile offsets (tile = 16n x 32k = 512 bf16 = 1KB, B-fragment order)
#define T_LA   0      // 13 nt x 2 kt   (lat_act_W, K padded 36->64) [legacy, unused by core]
#define T_IH   26     // 39 nt x 7 kt   (gru_Wih rows reordered: (group g, gate) triples)
#define T_HH   299    // 39 nt x 7 kt
#define T_P1   572    // 13 nt x 7 kt   (post1_W[:, :200])
#define T_PM   663    //  2 nt x 7 kt   (post_m_W) [legacy, unused]
#define T_POST 677    // 13 nt x 32 kt  (post1_W[:, 200:], K=1024)
#define T_PR1  1093   // 13 nt x 7 kt   (prior1_W)
#define T_CLA  1184   // 13 nt x 8 kt   (Wcomp = Wla_s@Wpm, kt7 = Wla_a part)
#define T_TOT  1288
#define NFRAG  (T_TOT * 64)

__device__ __forceinline__ u16 f2bf(float f){
  u32 x = __float_as_uint(f);
  return (u16)((x + 0x7FFFu + ((x >> 16) & 1u)) >> 16);
}
__device__ __forceinline__ float bf2f(u16 h){ return __uint_as_float(((u32)h) << 16); }

// hardware transcendentals (~1 ulp; saturate correctly at +-inf)
__device__ __forceinline__ float fexp2(float x){ float r; asm("v_exp_f32 %0, %1" : "=v"(r) : "v"(x)); return r; }
__device__ __forceinline__ float frcp (float x){ float r; asm("v_rcp_f32 %0, %1" : "=v"(r) : "v"(x)); return r; }
#define LOG2E 1.44269504f
__device__ __forceinline__ float fsigm(float x){ return frcp(1.0f + fexp2(-LOG2E * x)); }
__device__ __forceinline__ float ftanh(float x){ return 1.0f - 2.0f * frcp(1.0f + fexp2(2.0f * LOG2E * x)); }

__device__ __forceinline__ float stdf_(float x){
  float sp = fmaxf(x, 0.f) + log1pf(expf(-fabsf(x))) + 0.1f;
  return fminf(fmaxf(sp, 1e-6f), 10.0f);
}

// raw barrier: drain LDS ops only (lgkmcnt), do NOT drain vmcnt — keeps
// global weight prefetches in flight across phase boundaries (T4 pattern).
#define BAR() do { \
  asm volatile("s_waitcnt lgkmcnt(0)" ::: "memory"); \
  __builtin_amdgcn_s_barrier(); \
  asm volatile("" ::: "memory"); \
} while (0)

// scheduling pin: nothing may cross — prevents the compiler from sinking
// prefetch loads down to their consuming MFMA chain (the R2 failure mode).
#define SB() __builtin_amdgcn_sched_barrier(0)

// load one 7-tile weight unit (unit = row of 7 consecutive tiles)
#define LOAD7(dst, base, unit) do { \
  const u16* _p = (base) + ((((size_t)(unit))*7) << 9) + lane*8; \
  _Pragma("unroll") \
  for (int _k = 0; _k < 7; ++_k) dst[_k] = *(const bf16x8*)(_p + ((size_t)_k << 9)); \
} while (0)

// load one 8-tile CLA unit
#define LOAD8(dst, base, unit) do { \
  const u16* _p = (base) + ((((size_t)(unit))*8) << 9) + lane*8; \
  _Pragma("unroll") \
  for (int _k = 0; _k < 8; ++_k) dst[_k] = *(const bf16x8*)(_p + ((size_t)_k << 9)); \
} while (0)

#define CHAIN7(accv, Afr, buf) do { \
  _Pragma("unroll") \
  for (int _k = 0; _k < 7; ++_k) \
    accv = __builtin_amdgcn_mfma_f32_16x16x32_bf16(Afr[_k], buf[_k], accv, 0, 0, 0); \
} while (0)

#define CHAIN8(accv, Afr, buf) do { \
  _Pragma("unroll") \
  for (int _k = 0; _k < 8; ++_k) \
    accv = __builtin_amdgcn_mfma_f32_16x16x32_bf16(Afr[_k], buf[_k], accv, 0, 0, 0); \
} while (0)

// ---------------- kernel 1: pack weights into MFMA B-fragment tiles ----------------
__global__ __launch_bounds__(256) void prep2(
    const float* __restrict__ lat_act_W,
    const float* __restrict__ gru_Wih,
    const float* __restrict__ gru_Whh,
    const float* __restrict__ post1_W,
    const float* __restrict__ post_m_W,
    const float* __restrict__ prior1_W,
    u16* __restrict__ wbuf)
{
  int gid = blockIdx.x * 256 + threadIdx.x;
  if (gid >= NFRAG) return;
  int tile = gid >> 6, lane = gid & 63;
  int nl = lane & 15, qq = lane >> 4;

  if (tile >= T_CLA){                     // CLA: Wcomp = Wla_s @ Wpm (fp32), kt7 = Wla_a
    int lt = tile - T_CLA, nt = lt >> 3, kt = lt & 7;
    int row = nt*16 + nl;
    bool vn = row < 200;
    float wla[30];
    #pragma unroll
    for (int j = 0; j < 30; ++j) wla[j] = vn ? lat_act_W[(size_t)row*36 + j] : 0.f;
    __align__(16) u16 ov[8];
    #pragma unroll
    for (int j = 0; j < 8; ++j){
      float v = 0.f;
      if (kt < 7){
        int k = kt*32 + qq*8 + j;
        if (vn && k < 200){
          #pragma unroll
          for (int j2 = 0; j2 < 30; ++j2) v += wla[j2] * post_m_W[(size_t)j2*200 + k];
        }
      } else {
        int kk = qq*8 + j;
        if (vn && kk < 6) v = lat_act_W[(size_t)row*36 + 30 + kk];
      }
      ov[j] = f2bf(v);
    }
    *(uint4*)(wbuf + (size_t)gid*8) = *(const uint4*)ov;
    return;
  }

  const float* src = nullptr;
  long stride = 0; int row = 0, kbase = 0, kmax = 0, coff = 0; bool vn = false;
  if (tile < T_IH){                       // LA (legacy)
    int lt = tile, nt = lt >> 1, kt = lt & 1;
    row = nt*16 + nl; vn = row < 200; kbase = kt*32 + qq*8; kmax = 36;
    src = lat_act_W; stride = 36;
  } else if (tile < T_HH){                // IH (gate-triple reordered)
    int lt = tile - T_IH, nt = lt / 7, kt = lt - nt*7;
    int g = nt / 3, gate = nt - g*3, nn = g*16 + nl;
    vn = nn < 200; row = gate*200 + nn; kbase = kt*32 + qq*8; kmax = 200;
    src = gru_Wih; stride = 200;
  } else if (tile < T_P1){                // HH
    int lt = tile - T_HH, nt = lt / 7, kt = lt - nt*7;
    int g = nt / 3, gate = nt - g*3, nn = g*16 + nl;
    vn = nn < 200; row = gate*200 + nn; kbase = kt*32 + qq*8; kmax = 200;
    src = gru_Whh; stride = 200;
  } else if (tile < T_PM){                // P1 (post1 h-part)
    int lt = tile - T_P1, nt = lt / 7, kt = lt - nt*7;
    row = nt*16 + nl; vn = row < 200; kbase = kt*32 + qq*8; kmax = 200;
    src = post1_W; stride = 1224;
  } else if (tile < T_POST){              // PM (legacy)
    int lt = tile - T_PM, nt = lt / 7, kt = lt - nt*7;
    row = nt*16 + nl; vn = row < 30; kbase = kt*32 + qq*8; kmax = 200;
    src = post_m_W; stride = 200;
  } else if (tile < T_PR1){               // POST (post1 e-part, K=1024)
    int lt = tile - T_POST, nt = lt >> 5, kt = lt & 31;
    row = nt*16 + nl; vn = row < 200; kbase = kt*32 + qq*8; kmax = 1024; coff = 200;
    src = post1_W; stride = 1224;
  } else {                                // PR1
    int lt = tile - T_PR1, nt = lt / 7, kt = lt - nt*7;
    row = nt*16 + nl; vn = row < 200; kbase = kt*32 + qq*8; kmax = 200;
    src = prior1_W; stride = 200;
  }
  __align__(16) u16 ov[8];
  #pragma unroll
  for (int j = 0; j < 8; ++j){
    int k = kbase + j;
    float v = (vn && k < kmax) ? src[(size_t)row*stride + coff + k] : 0.f;
    ov[j] = f2bf(v);
  }
  *(uint4*)(wbuf + (size_t)gid*8) = *(const uint4*)ov;
}

// ---------------- kernel 2: Epost = e[:,1:] @ post1_W[:,200:].T + post1_b ----------------
__global__ __launch_bounds__(256) void epost_kernel(
    const float* __restrict__ e,
    const float* __restrict__ post1_b,
    const u16* __restrict__ wbuf,
    u16* __restrict__ Epost)
{
  const int tid = threadIdx.x;
  const int wave = tid >> 6, lane = tid & 63, nl = lane & 15, q = lane >> 4;
  const int m0 = blockIdx.x * 64;
  const int tt = m0 >> 9;
  const int b0 = (m0 & 511) + wave*16;
  const u16* wPOST = wbuf + (size_t)T_POST * 512 + lane*8;

  f32x4 acc[13];
  #pragma unroll
  for (int i = 0; i < 13; ++i) acc[i] = (f32x4){0.f,0.f,0.f,0.f};

  const float* arow = e + ((size_t)(b0 + nl)*(Tq + 1) + (tt + 1))*NEMB + q*8;

  for (int kt = 0; kt < 32; ++kt){
    float4 f0 = *(const float4*)(arow + (size_t)kt*32);
    float4 f1 = *(const float4*)(arow + (size_t)kt*32 + 4);
    bf16x8 afr;
    afr[0]=(short)f2bf(f0.x); afr[1]=(short)f2bf(f0.y); afr[2]=(short)f2bf(f0.z); afr[3]=(short)f2bf(f0.w);
    afr[4]=(short)f2bf(f1.x); afr[5]=(short)f2bf(f1.y); afr[6]=(short)f2bf(f1.z); afr[7]=(short)f2bf(f1.w);
    #pragma unroll
    for (int nt = 0; nt < 13; ++nt){
      bf16x8 b = *(const bf16x8*)(wPOST + (((size_t)(nt*32 + kt)) << 9));
      acc[nt] = __builtin_amdgcn_mfma_f32_16x16x32_bf16(afr, b, acc[nt], 0, 0, 0);
    }
  }
  #pragma unroll
  for (int nt = 0; nt < 13; ++nt){
    int n = nt*16 + nl;
    if (n < 200){
      float bb = post1_b[n];
      #pragma unroll
      for (int r = 0; r < 4; ++r){
        int m = m0 + wave*16 + q*4 + r;
        Epost[(size_t)m*NST + n] = f2bf(acc[nt][r] + bb);
      }
    }
  }
}

// ---------------- kernel 3: sequential MFMA core (32 blocks x 16 rows, 8 waves) ----------------
// 3-phase step (LAT -> GATES -> P1), QM phase eliminated via composite
// Wcomp = Wla_s@Wpm (recurrence consumes zq directly). Depth-3 weight ring
// with sched_barrier(0)-pinned 2-unit lookahead. Loop-top invariant:
// b0 = CLA(wave) in flight.
__global__ __launch_bounds__(512, 2) void core_kernel(
    const float* __restrict__ u,
    const float* __restrict__ lat_act_b,
    const float* __restrict__ lat_act_W,
    const float* __restrict__ post_m_b,
    const float* __restrict__ gru_bih,
    const float* __restrict__ gru_bhh,
    const u16* __restrict__ wbuf,
    const u16* __restrict__ Epost,
    float* __restrict__ out_states)
{
  __shared__ __align__(16) u16 xs[16][40];        // [ u(6) | pad->32 ] bf16 (A kt7 of LAT)
  __shared__ __align__(16) u16 xb[16][232];       // lat output bf16, K-pad 224
  __shared__ __align__(16) u16 hb[2][16][232];    // h bf16 mirror, double-buffered
  __shared__ __align__(16) u16 zqb[16][232];      // zq bf16 (LAT input at t+1)

  const int tid  = threadIdx.x;
  const int wave = tid >> 6;
  const int lane = tid & 63;
  const int nl   = lane & 15;
  const int q    = lane >> 4;
  const int row0 = blockIdx.x * 16;

  const u16* wIH  = wbuf + (size_t)T_IH  * 512;
  const u16* wHH  = wbuf + (size_t)T_HH  * 512;
  const u16* wP1  = wbuf + (size_t)T_P1  * 512;
  const u16* wCLA = wbuf + (size_t)T_CLA * 512;

  const bool two  = (wave < 5);          // has a second n-tile (wave+8 < 13)
  const int  cmax = two ? 2 : 1;

  // prime the ring: b0 = CLA(wave)
  bf16x8 b0[8], b1[8], b2[8];
  LOAD8(b0, wCLA, wave);

  for (int i = tid; i < 16*40;  i += 512) ((u16*)xs)[i] = 0;
  for (int i = tid; i < 16*232; i += 512){
    ((u16*)xb)[i] = 0; ((u16*)hb[0])[i] = 0; ((u16*)hb[1])[i] = 0; ((u16*)zqb)[i] = 0;
  }

  // --- register-persistent biases (loaded once) ---
  float latb_r[2]  = {0.f, 0.f};         // t==0 bias (no bpm fold)
  float latb2_r[2] = {0.f, 0.f};         // t>=1 bias: + Wla_s . bpm
  float brz_r[2][2] = {};                // bih+bhh pre-summed, gates r,z
  float bin_r[2] = {}, bhn_r[2] = {};    // n-gate parts (kept separate)
  #pragma unroll
  for (int c = 0; c < 2; ++c){
    if (c < cmax){
      const int n = (wave + 8*c)*16 + nl;
      const bool v = (n < 200);
      if (v){
        latb_r[c] = lat_act_b[n];
        float s2 = 0.f;
        #pragma unroll
        for (int j = 0; j < 30; ++j) s2 += lat_act_W[(size_t)n*36 + j] * post_m_b[j];
        latb2_r[c] = latb_r[c] + s2;
        brz_r[c][0] = gru_bih[n]       + gru_bhh[n];
        brz_r[c][1] = gru_bih[200 + n] + gru_bhh[200 + n];
        bin_r[c]    = gru_bih[400 + n];
        bhn_r[c]    = gru_bhh[400 + n];
      }
    }
  }

  float hreg[2][4] = {};                 // fp32 master h (same-lane read/write)

  const int ur = tid / 6, uk = tid - ur*6;
  const bool uth = (tid < 96);
  float u_reg = uth ? u[((size_t)(row0 + ur)*Tq + 0)*NACT + uk] : 0.f;

  BAR();

  for (int t = 0; t < Tq; ++t){
    const int pb = t & 1;
    if (uth) xs[ur][uk] = f2bf(u_reg);
    BAR();                                           // B0 (zqb from prev P1 + xs visible)

    // ---- Epost prefetch for this step (consumed in P1 epilogue) ----
    u32 ep0[4], ep1[4];
    {
      const int n0 = wave*16 + nl;                   // always < 200
      const int n1 = n0 + 128;
      const u16* eb = Epost + ((size_t)t*Bq + row0 + q*4)*NST;
      #pragma unroll
      for (int r = 0; r < 4; ++r){
        ep0[r] = eb[(size_t)r*NST + n0];
        ep1[r] = (two && n1 < 200) ? (u32)eb[(size_t)r*NST + n1] : 0u;
      }
    }

    // ---- read ah (hb[pb] stable since GATES of prev step) ----
    bf16x8 ah[7];
    #pragma unroll
    for (int kt = 0; kt < 7; ++kt)
      ah[kt] = *(const bf16x8*)(&hb[pb][nl][kt*32 + q*8]);

    // ---- LAT: x = relu(Wcomp.zq + Wla_a.a + b) ----
    {
      bf16x8 aL[8];
      #pragma unroll
      for (int kt = 0; kt < 7; ++kt)
        aL[kt] = *(const bf16x8*)(&zqb[nl][kt*32 + q*8]);
      aL[7] = *(const bf16x8*)(&xs[nl][q*8]);

      f32x4 L0 = {0.f,0.f,0.f,0.f}, L1 = {0.f,0.f,0.f,0.f};
      if (two) { LOAD8(b1, wCLA, wave + 8); }
      LOAD7(b2, wIH, wave*3);
      SB();
      CHAIN8(L0, aL, b0);                            // b0 = CLA(wave)
      LOAD7(b0, wHH, wave*3);
      SB();
      if (two) { CHAIN8(L1, aL, b1); }

      #pragma unroll
      for (int c = 0; c < 2; ++c){
        if (c < cmax){
          const f32x4& L = c ? L1 : L0;
          const int n = (wave + 8*c)*16 + nl;
          const float lb = (t == 0) ? latb_r[c] : latb2_r[c];
          if (n < 200){
            #pragma unroll
            for (int r = 0; r < 4; ++r)
              xb[q*4 + r][n] = f2bf(fmaxf(L[r] + lb, 0.f));
          }
        }
      }
    }
    BAR();                                           // B1

    // ---- GATES: ring with pinned 2-unit lookahead ----
    // entry per c: b2 = IH(gu), b0 = HH(gu), b1 free
    {
      bf16x8 ax[7];
      #pragma unroll
      for (int kt = 0; kt < 7; ++kt)
        ax[kt] = *(const bf16x8*)(&xb[nl][kt*32 + q*8]);
      if (uth && t + 1 < Tq) u_reg = u[((size_t)(row0 + ur)*Tq + (t + 1))*NACT + uk];

      float* os = out_states + ((size_t)t*Bq + row0)*NST;

      #pragma unroll
      for (int c = 0; c < 2; ++c){
        if (c < cmax){
          const int g  = wave + 8*c;
          const int gu = g*3;
          const bool last = (c + 1 == cmax);
          f32x4 a0  = {0.f,0.f,0.f,0.f};             // r gate (ih+hh merged)
          f32x4 a1  = {0.f,0.f,0.f,0.f};             // z gate (ih+hh merged)
          f32x4 a2i = {0.f,0.f,0.f,0.f};             // n gate ih
          f32x4 a2h = {0.f,0.f,0.f,0.f};             // n gate hh

          LOAD7(b1, wIH, gu + 1);  SB();  CHAIN7(a0, ax, b2);
          LOAD7(b2, wHH, gu + 1);  SB();  CHAIN7(a0, ah, b0);
          LOAD7(b0, wIH, gu + 2);  SB();  CHAIN7(a1, ax, b1);
          LOAD7(b1, wHH, gu + 2);  SB();  CHAIN7(a1, ah, b2);
          if (last) { LOAD7(b2, wP1, wave); }
          else      { LOAD7(b2, wIH, (wave + 8)*3); }
          SB();  CHAIN7(a2i, ax, b0);
          if (last) { LOAD8(b0, wCLA, wave); }       // next-step CLA(wave)
          else      { LOAD7(b0, wHH, (wave + 8)*3); }
          SB();  CHAIN7(a2h, ah, b1);

          const int n = g*16 + nl;
          if (n < 200){
            #pragma unroll
            for (int r = 0; r < 4; ++r){
              const int m = q*4 + r;
              float rg = fsigm(a0[r] + brz_r[c][0]);
              float zg = fsigm(a1[r] + brz_r[c][1]);
              float ng = ftanh(a2i[r] + bin_r[c] + rg*(a2h[r] + bhn_r[c]));
              float hn = (1.f - zg)*ng + zg*hreg[c][r];
              hreg[c][r] = hn;
              hb[pb ^ 1][m][n] = f2bf(hn);
              os[(size_t)m*NST + n] = hn;
            }
          }
        }
      }
    }
    BAR();                                           // B2

    // ---- P1: zq = relu(h_new @ Wp1^T + Epost) ----
    // entry: b2 = P1(wave), b0 = CLA(wave) [kept for next LAT], b1 free
    {
      bf16x8 ah2[7];
      #pragma unroll
      for (int kt = 0; kt < 7; ++kt)
        ah2[kt] = *(const bf16x8*)(&hb[pb ^ 1][nl][kt*32 + q*8]);
      f32x4 aP0 = {0.f,0.f,0.f,0.f}, aP1 = {0.f,0.f,0.f,0.f};
      if (two) { LOAD7(b1, wP1, wave + 8); }
      SB();
      CHAIN7(aP0, ah2, b2);
      SB();
      if (two) { CHAIN7(aP1, ah2, b1); }
      {
        const int n0 = wave*16 + nl;
        #pragma unroll
        for (int r = 0; r < 4; ++r)
          zqb[q*4 + r][n0] = f2bf(fmaxf(aP0[r] + bf2f((u16)ep0[r]), 0.f));
        if (two){
          const int n1 = n0 + 128;
          if (n1 < 200){
            #pragma unroll
            for (int r = 0; r < 4; ++r)
              zqb[q*4 + r][n1] = f2bf(fmaxf(aP1[r] + bf2f((u16)ep1[r]), 0.f));
          }
        }
      }
    }
    // loop back; B0 of next iteration synchronizes. Invariant: b0 = CLA(wave).
  }
}

// ---------------- kernel 4: prior branch + qm/qs heads ----------------
__global__ __launch_bounds__(256) void phasec_kernel(
    const float* __restrict__ states,
    const u16* __restrict__ Epost,
    const u16* __restrict__ wbuf,
    const float* __restrict__ prior1_b,
    const float* __restrict__ prior_m_W, const float* __restrict__ prior_m_b,
    const float* __restrict__ prior_s_W, const float* __restrict__ prior_s_b,
    const float* __restrict__ post_m_W,  const float* __restrict__ post_m_b,
    const float* __restrict__ post_s_W,  const float* __restrict__ post_s_b,
    float* __restrict__ pm, float* __restrict__ ps,
    float* __restrict__ qm, float* __restrict__ qs)
{
  __shared__ __align__(16) u16 stb[32][232];
  __shared__ float zp[32][208];
  __shared__ float zqf[32][208];
  const int tid = threadIdx.x, wave = tid >> 6, lane = tid & 63, nl = lane & 15, q = lane >> 4;
  const size_t m0 = (size_t)blockIdx.x * 32;
  const u16* wP1  = wbuf + (size_t)T_P1 * 512;
  const u16* wPR1 = wbuf + (size_t)T_PR1 * 512;

  for (int i = tid; i < 32*200; i += 256){
    int r = i / 200, c = i - r*200;
    stb[r][c] = f2bf(states[(m0 + r)*NST + c]);
  }
  for (int i = tid; i < 32*32; i += 256){
    int r = i >> 5, c = i & 31;
    stb[r][200 + c] = 0;
  }
  __syncthreads();

  {
    const int rowb = (wave & 1) * 16;
    const bool doZQ = (wave >= 2);
    const u16* wmat = doZQ ? wP1 : wPR1;
    bf16x8 a7[7];
    #pragma unroll
    for (int kt = 0; kt < 7; ++kt)
      a7[kt] = *(const bf16x8*)(&stb[rowb + nl][kt*32 + q*8]);
    for (int nt = 0; nt < 13; ++nt){
      f32x4 a = {0.f, 0.f, 0.f, 0.f};
      #pragma unroll
      for (int kt = 0; kt < 7; ++kt){
        bf16x8 b = *(const bf16x8*)(wmat + (((size_t)(nt*7 + kt)) << 9) + lane*8);
        a = __builtin_amdgcn_mfma_f32_16x16x32_bf16(a7[kt], b, a, 0, 0, 0);
      }
      int n = nt*16 + nl;
      if (n < 200){
        #pragma unroll
        for (int r = 0; r < 4; ++r){
          int m = rowb + q*4 + r;
          if (doZQ){
            float v = a[r] + bf2f(Epost[(m0 + m)*NST + n]);
            zqf[m][n] = fmaxf(v, 0.f);
          } else {
            float v = a[r] + prior1_b[n];
            zp[m][n] = fmaxf(v, 0.f);
          }
        }
      }
    }
  }
  __syncthreads();

  // heads: 0=pm(zp), 1=ps(zp,std), 2=qm(zqf), 3=qs(zqf,std) — fp32 dots
  for (int i = tid; i < 32*120; i += 256){
    int r = i / 120, rem = i - r*120;
    int head = rem / 30, l = rem - head*30;
    const float* wrow = (head == 0 ? prior_m_W : head == 1 ? prior_s_W :
                         head == 2 ? post_m_W  : post_s_W) + (size_t)l*NST;
    const float* vec = (head >= 2) ? &zqf[r][0] : &zp[r][0];
    float acc = 0.f;
    #pragma unroll 10
    for (int c = 0; c < 50; ++c){
      float4 wv = *(const float4*)(wrow + c*4);
      acc = fmaf(wv.x, vec[c*4 + 0], acc);
      acc = fmaf(wv.y, vec[c*4 + 1], acc);
      acc = fmaf(wv.z, vec[c*4 + 2], acc);
      acc = fmaf(wv.w, vec[c*4 + 3], acc);
    }
    float bias = (head == 0 ? prior_m_b : head == 1 ? prior_s_b :
                  head == 2 ? post_m_b  : post_s_b)[l];
    float v = acc + bias;
    if (head == 1 || head == 3) v = stdf_(v);
    float* o = head == 0 ? pm : head == 1 ? ps : head == 2 ? qm : qs;
    o[(m0 + r)*NLAT + l] = v;
  }
}

// ---------------- launcher ----------------
extern "C" void kernel_launch(void* const* d_in, const int* in_sizes, int n_in,
                              void* d_out, int out_size, void* d_ws, size_t ws_size,
                              hipStream_t stream)
{
  const float* e         = (const float*)d_in[0];
  const float* u         = (const float*)d_in[1];
  const float* lat_act_W = (const float*)d_in[2];
  const float* lat_act_b = (const float*)d_in[3];
  const float* gru_Wih   = (const float*)d_in[4];
  const float* gru_Whh   = (const float*)d_in[5];
  const float* gru_bih   = (const float*)d_in[6];
  const float* gru_bhh   = (const float*)d_in[7];
  const float* prior1_W  = (const float*)d_in[8];
  const float* prior1_b  = (const float*)d_in[9];
  const float* prior_m_W = (const float*)d_in[10];
  const float* prior_m_b = (const float*)d_in[11];
  const float* prior_s_W = (const float*)d_in[12];
  const float* prior_s_b = (const float*)d_in[13];
  const float* post1_W   = (const float*)d_in[14];
  const float* post1_b   = (const float*)d_in[15];
  const float* post_m_W  = (const float*)d_in[16];
  const float* post_m_b  = (const float*)d_in[17];
  const float* post_s_W  = (const float*)d_in[18];
  const float* post_s_b  = (const float*)d_in[19];

  float* out    = (float*)d_out;
  float* states = out;                       // [100][512][200]
  float* pm     = out + 10240000;
  float* ps     = out + 11776000;
  float* qm     = out + 13312000;
  float* qs     = out + 14848000;

  u16* Epost = (u16*)d_ws;                               // 10,240,000 bf16 = 20.48 MB
  u16* wbuf  = (u16*)((char*)d_ws + 20480000);           // 1.32 MB packed weights

  hipLaunchKernelGGL(prep2, dim3((NFRAG + 255) / 256), dim3(256), 0, stream,
                     lat_act_W, gru_Wih, gru_Whh, post1_W, post_m_W, prior1_W, wbuf);

  hipLaunchKernelGGL(epost_kernel, dim3(800), dim3(256), 0, stream,
                     e, post1_b, wbuf, Epost);

  hipLaunchKernelGGL(core_kernel, dim3(32), dim3(512), 0, stream,
                     u, lat_act_b, lat_act_W, post_m_b, gru_bih, gru_bhh,
                     wbuf, Epost, states);

  hipLaunchKernelGGL(phasec_kernel, dim3(1600), dim3(256), 0, stream,
                     states, Epost, wbuf, prior1_b,
                     prior_m_W, prior_m_b, prior_s_W, prior_s_b,
                     post_m_W, post_m_b, post_s_W, post_s_b,
                     pm, ps, qm, qs);
}

// Round 4
// 1852.730 us; speedup vs baseline: 1.1611x; 1.1611x over previous
//
#include <hip/hip_runtime.h>
#include <cstdint>

typedef unsigned int u32;
typedef unsigned short u16;
typedef short bf16x8 __attribute__((ext_vector_type(8)));
typedef float f32x4 __attribute__((ext_vector_type(4)));

#define Bq 512
#define Tq 100
#define NST 200
#define NLAT 30
#define NEMB 1024
#define NACT 6

// packed weight tile offsets (tile = 16n x 32k = 512 bf16 = 1KB, B-fragment order)
#define T_LA   0      // 13 nt x 2 kt   (lat_act_W, K padded 36->64) [legacy, unused by core]
#define T_IH   26     // 39 nt x 7 kt   (gru_Wih rows reordered: (group g, gate) triples)
#define T_HH   299    // 39 nt x 7 kt
#define T_P1   572    // 13 nt x 7 kt   (post1_W[:, :200])
#define T_PM   663    //  2 nt x 7 kt   (post_m_W) [legacy, unused]
#define T_POST 677    // 13 nt x 32 kt  (post1_W[:, 200:], K=1024)
#define T_PR1  1093   // 13 nt x 7 kt   (prior1_W)
#define T_CLA  1184   // 13 nt x 8 kt   (Wcomp = Wla_s@Wpm, kt7 = Wla_a part)
#define T_HD   1288   // 4 heads x 2 nt x 7 kt (prior_m, prior_s, post_m, post_s)
#define T_TOT  1344
#define NFRAG  (T_TOT * 64)

__device__ __forceinline__ u16 f2bf(float f){
  u32 x = __float_as_uint(f);
  return (u16)((x + 0x7FFFu + ((x >> 16) & 1u)) >> 16);
}
__device__ __forceinline__ float bf2f(u16 h){ return __uint_as_float(((u32)h) << 16); }

// hardware transcendentals (~1 ulp; saturate correctly at +-inf)
__device__ __forceinline__ float fexp2(float x){ float r; asm("v_exp_f32 %0, %1" : "=v"(r) : "v"(x)); return r; }
__device__ __forceinline__ float frcp (float x){ float r; asm("v_rcp_f32 %0, %1" : "=v"(r) : "v"(x)); return r; }
#define LOG2E 1.44269504f
__device__ __forceinline__ float fsigm(float x){ return frcp(1.0f + fexp2(-LOG2E * x)); }
__device__ __forceinline__ float ftanh(float x){ return 1.0f - 2.0f * frcp(1.0f + fexp2(2.0f * LOG2E * x)); }

__device__ __forceinline__ float stdf_(float x){
  float sp = fmaxf(x, 0.f) + log1pf(expf(-fabsf(x))) + 0.1f;
  return fminf(fmaxf(sp, 1e-6f), 10.0f);
}

// raw barrier: drain LDS ops only (lgkmcnt), do NOT drain vmcnt — keeps
// global weight prefetches in flight across phase boundaries (T4 pattern).
#define BAR() do { \
  asm volatile("s_waitcnt lgkmcnt(0)" ::: "memory"); \
  __builtin_amdgcn_s_barrier(); \
  asm volatile("" ::: "memory"); \
} while (0)

// scheduling pin: nothing may cross — prevents the compiler from sinking
// prefetch loads down to their consuming MFMA chain.
#define SB() __builtin_amdgcn_sched_barrier(0)

// load one 7-tile weight unit (unit = row of 7 consecutive tiles)
#define LOAD7(dst, base, unit) do { \
  const u16* _p = (base) + ((((size_t)(unit))*7) << 9) + lane*8; \
  _Pragma("unroll") \
  for (int _k = 0; _k < 7; ++_k) dst[_k] = *(const bf16x8*)(_p + ((size_t)_k << 9)); \
} while (0)

// load one 8-tile CLA unit
#define LOAD8(dst, base, unit) do { \
  const u16* _p = (base) + ((((size_t)(unit))*8) << 9) + lane*8; \
  _Pragma("unroll") \
  for (int _k = 0; _k < 8; ++_k) dst[_k] = *(const bf16x8*)(_p + ((size_t)_k << 9)); \
} while (0)

#define CHAIN7(accv, Afr, buf) do { \
  _Pragma("unroll") \
  for (int _k = 0; _k < 7; ++_k) \
    accv = __builtin_amdgcn_mfma_f32_16x16x32_bf16(Afr[_k], buf[_k], accv, 0, 0, 0); \
} while (0)

#define CHAIN8(accv, Afr, buf) do { \
  _Pragma("unroll") \
  for (int _k = 0; _k < 8; ++_k) \
    accv = __builtin_amdgcn_mfma_f32_16x16x32_bf16(Afr[_k], buf[_k], accv, 0, 0, 0); \
} while (0)

// ---------------- kernel 1: pack weights into MFMA B-fragment tiles ----------------
__global__ __launch_bounds__(256) void prep2(
    const float* __restrict__ lat_act_W,
    const float* __restrict__ gru_Wih,
    const float* __restrict__ gru_Whh,
    const float* __restrict__ post1_W,
    const float* __restrict__ post_m_W,
    const float* __restrict__ prior1_W,
    const float* __restrict__ prior_m_W,
    const float* __restrict__ prior_s_W,
    const float* __restrict__ post_s_W,
    u16* __restrict__ wbuf)
{
  int gid = blockIdx.x * 256 + threadIdx.x;
  if (gid >= NFRAG) return;
  int tile = gid >> 6, lane = gid & 63;
  int nl = lane & 15, qq = lane >> 4;

  if (tile >= T_HD){                      // HD: 4 head matrices, 30x200 each
    int lt = tile - T_HD;
    int hd = lt / 14, rem = lt - hd*14;
    int nt = rem / 7, kt = rem - nt*7;
    int row = nt*16 + nl;
    bool vn = row < 30;
    const float* src = hd == 0 ? prior_m_W : hd == 1 ? prior_s_W :
                       hd == 2 ? post_m_W  : post_s_W;
    __align__(16) u16 ov[8];
    #pragma unroll
    for (int j = 0; j < 8; ++j){
      int k = kt*32 + qq*8 + j;
      float v = (vn && k < 200) ? src[(size_t)row*200 + k] : 0.f;
      ov[j] = f2bf(v);
    }
    *(uint4*)(wbuf + (size_t)gid*8) = *(const uint4*)ov;
    return;
  }

  if (tile >= T_CLA){                     // CLA: Wcomp = Wla_s @ Wpm (fp32), kt7 = Wla_a
    int lt = tile - T_CLA, nt = lt >> 3, kt = lt & 7;
    int row = nt*16 + nl;
    bool vn = row < 200;
    float wla[30];
    #pragma unroll
    for (int j = 0; j < 30; ++j) wla[j] = vn ? lat_act_W[(size_t)row*36 + j] : 0.f;
    __align__(16) u16 ov[8];
    #pragma unroll
    for (int j = 0; j < 8; ++j){
      float v = 0.f;
      if (kt < 7){
        int k = kt*32 + qq*8 + j;
        if (vn && k < 200){
          #pragma unroll
          for (int j2 = 0; j2 < 30; ++j2) v += wla[j2] * post_m_W[(size_t)j2*200 + k];
        }
      } else {
        int kk = qq*8 + j;
        if (vn && kk < 6) v = lat_act_W[(size_t)row*36 + 30 + kk];
      }
      ov[j] = f2bf(v);
    }
    *(uint4*)(wbuf + (size_t)gid*8) = *(const uint4*)ov;
    return;
  }

  const float* src = nullptr;
  long stride = 0; int row = 0, kbase = 0, kmax = 0, coff = 0; bool vn = false;
  if (tile < T_IH){                       // LA (legacy)
    int lt = tile, nt = lt >> 1, kt = lt & 1;
    row = nt*16 + nl; vn = row < 200; kbase = kt*32 + qq*8; kmax = 36;
    src = lat_act_W; stride = 36;
  } else if (tile < T_HH){                // IH (gate-triple reordered)
    int lt = tile - T_IH, nt = lt / 7, kt = lt - nt*7;
    int g = nt / 3, gate = nt - g*3, nn = g*16 + nl;
    vn = nn < 200; row = gate*200 + nn; kbase = kt*32 + qq*8; kmax = 200;
    src = gru_Wih; stride = 200;
  } else if (tile < T_P1){                // HH
    int lt = tile - T_HH, nt = lt / 7, kt = lt - nt*7;
    int g = nt / 3, gate = nt - g*3, nn = g*16 + nl;
    vn = nn < 200; row = gate*200 + nn; kbase = kt*32 + qq*8; kmax = 200;
    src = gru_Whh; stride = 200;
  } else if (tile < T_PM){                // P1 (post1 h-part)
    int lt = tile - T_P1, nt = lt / 7, kt = lt - nt*7;
    row = nt*16 + nl; vn = row < 200; kbase = kt*32 + qq*8; kmax = 200;
    src = post1_W; stride = 1224;
  } else if (tile < T_POST){              // PM (legacy)
    int lt = tile - T_PM, nt = lt / 7, kt = lt - nt*7;
    row = nt*16 + nl; vn = row < 30; kbase = kt*32 + qq*8; kmax = 200;
    src = post_m_W; stride = 200;
  } else if (tile < T_PR1){               // POST (post1 e-part, K=1024)
    int lt = tile - T_POST, nt = lt >> 5, kt = lt & 31;
    row = nt*16 + nl; vn = row < 200; kbase = kt*32 + qq*8; kmax = 1024; coff = 200;
    src = post1_W; stride = 1224;
  } else {                                // PR1
    int lt = tile - T_PR1, nt = lt / 7, kt = lt - nt*7;
    row = nt*16 + nl; vn = row < 200; kbase = kt*32 + qq*8; kmax = 200;
    src = prior1_W; stride = 200;
  }
  __align__(16) u16 ov[8];
  #pragma unroll
  for (int j = 0; j < 8; ++j){
    int k = kbase + j;
    float v = (vn && k < kmax) ? src[(size_t)row*stride + coff + k] : 0.f;
    ov[j] = f2bf(v);
  }
  *(uint4*)(wbuf + (size_t)gid*8) = *(const uint4*)ov;
}

// ---------------- kernel 2: Epost = e[:,1:] @ post1_W[:,200:].T + post1_b ----------------
__global__ __launch_bounds__(256) void epost_kernel(
    const float* __restrict__ e,
    const float* __restrict__ post1_b,
    const u16* __restrict__ wbuf,
    u16* __restrict__ Epost)
{
  const int tid = threadIdx.x;
  const int wave = tid >> 6, lane = tid & 63, nl = lane & 15, q = lane >> 4;
  const int m0 = blockIdx.x * 64;
  const int tt = m0 >> 9;
  const int b0 = (m0 & 511) + wave*16;
  const u16* wPOST = wbuf + (size_t)T_POST * 512 + lane*8;

  f32x4 acc[13];
  #pragma unroll
  for (int i = 0; i < 13; ++i) acc[i] = (f32x4){0.f,0.f,0.f,0.f};

  const float* arow = e + ((size_t)(b0 + nl)*(Tq + 1) + (tt + 1))*NEMB + q*8;

  for (int kt = 0; kt < 32; ++kt){
    float4 f0 = *(const float4*)(arow + (size_t)kt*32);
    float4 f1 = *(const float4*)(arow + (size_t)kt*32 + 4);
    bf16x8 afr;
    afr[0]=(short)f2bf(f0.x); afr[1]=(short)f2bf(f0.y); afr[2]=(short)f2bf(f0.z); afr[3]=(short)f2bf(f0.w);
    afr[4]=(short)f2bf(f1.x); afr[5]=(short)f2bf(f1.y); afr[6]=(short)f2bf(f1.z); afr[7]=(short)f2bf(f1.w);
    #pragma unroll
    for (int nt = 0; nt < 13; ++nt){
      bf16x8 b = *(const bf16x8*)(wPOST + (((size_t)(nt*32 + kt)) << 9));
      acc[nt] = __builtin_amdgcn_mfma_f32_16x16x32_bf16(afr, b, acc[nt], 0, 0, 0);
    }
  }
  #pragma unroll
  for (int nt = 0; nt < 13; ++nt){
    int n = nt*16 + nl;
    if (n < 200){
      float bb = post1_b[n];
      #pragma unroll
      for (int r = 0; r < 4; ++r){
        int m = m0 + wave*16 + q*4 + r;
        Epost[(size_t)m*NST + n] = f2bf(acc[nt][r] + bb);
      }
    }
  }
}

// ---------------- kernel 3: sequential MFMA core (32 blocks x 16 rows, 8 waves) ----------------
// 3-phase step (LAT -> GATES -> P1). Depth-3 weight ring with
// sched_barrier(0)-pinned 2-unit lookahead. amdgpu_waves_per_eu(2,2) pins the
// occupancy target at the true resident value (1 block/CU = 2 waves/SIMD) so
// the register allocator gets the full 256-VGPR budget and the ring stays in
// registers (R2/R3 failure: allocator squeezed to 128, spilling the pipeline).
__global__ __attribute__((amdgpu_waves_per_eu(2, 2))) __launch_bounds__(512)
void core_kernel(
    const float* __restrict__ u,
    const float* __restrict__ lat_act_b,
    const float* __restrict__ lat_act_W,
    const float* __restrict__ post_m_b,
    const float* __restrict__ gru_bih,
    const float* __restrict__ gru_bhh,
    const u16* __restrict__ wbuf,
    const u16* __restrict__ Epost,
    float* __restrict__ out_states)
{
  __shared__ __align__(16) u16 xs[16][40];        // [ u(6) | pad->32 ] bf16 (A kt7 of LAT)
  __shared__ __align__(16) u16 xb[16][232];       // lat output bf16, K-pad 224
  __shared__ __align__(16) u16 hb[2][16][232];    // h bf16 mirror, double-buffered
  __shared__ __align__(16) u16 zqb[16][232];      // zq bf16 (LAT input at t+1)

  const int tid  = threadIdx.x;
  const int wave = tid >> 6;
  const int lane = tid & 63;
  const int nl   = lane & 15;
  const int q    = lane >> 4;
  const int row0 = blockIdx.x * 16;

  const u16* wIH  = wbuf + (size_t)T_IH  * 512;
  const u16* wHH  = wbuf + (size_t)T_HH  * 512;
  const u16* wP1  = wbuf + (size_t)T_P1  * 512;
  const u16* wCLA = wbuf + (size_t)T_CLA * 512;

  const bool two  = (wave < 5);          // has a second n-tile (wave+8 < 13)
  const int  cmax = two ? 2 : 1;

  // prime the ring: b0 = CLA(wave)
  bf16x8 b0[8], b1[8], b2[8];
  LOAD8(b0, wCLA, wave);

  for (int i = tid; i < 16*40;  i += 512) ((u16*)xs)[i] = 0;
  for (int i = tid; i < 16*232; i += 512){
    ((u16*)xb)[i] = 0; ((u16*)hb[0])[i] = 0; ((u16*)hb[1])[i] = 0; ((u16*)zqb)[i] = 0;
  }

  // --- register-persistent biases (loaded once) ---
  float latb_r[2]  = {0.f, 0.f};         // t==0 bias (no bpm fold)
  float latb2_r[2] = {0.f, 0.f};         // t>=1 bias: + Wla_s . bpm
  float brz_r[2][2] = {};                // bih+bhh pre-summed, gates r,z
  float bin_r[2] = {}, bhn_r[2] = {};    // n-gate parts (kept separate)
  #pragma unroll
  for (int c = 0; c < 2; ++c){
    if (c < cmax){
      const int n = (wave + 8*c)*16 + nl;
      const bool v = (n < 200);
      if (v){
        latb_r[c] = lat_act_b[n];
        float s2 = 0.f;
        #pragma unroll
        for (int j = 0; j < 30; ++j) s2 += lat_act_W[(size_t)n*36 + j] * post_m_b[j];
        latb2_r[c] = latb_r[c] + s2;
        brz_r[c][0] = gru_bih[n]       + gru_bhh[n];
        brz_r[c][1] = gru_bih[200 + n] + gru_bhh[200 + n];
        bin_r[c]    = gru_bih[400 + n];
        bhn_r[c]    = gru_bhh[400 + n];
      }
    }
  }

  float hreg[2][4] = {};                 // fp32 master h (same-lane read/write)

  const int ur = tid / 6, uk = tid - ur*6;
  const bool uth = (tid < 96);
  float u_reg = uth ? u[((size_t)(row0 + ur)*Tq + 0)*NACT + uk] : 0.f;

  BAR();

  for (int t = 0; t < Tq; ++t){
    const int pb = t & 1;
    if (uth) xs[ur][uk] = f2bf(u_reg);
    BAR();                                           // B0 (zqb from prev P1 + xs visible)

    // ---- Epost prefetch for this step (consumed in P1 epilogue) ----
    u32 ep0[4], ep1[4];
    {
      const int n0 = wave*16 + nl;                   // always < 200
      const int n1 = n0 + 128;
      const u16* eb = Epost + ((size_t)t*Bq + row0 + q*4)*NST;
      #pragma unroll
      for (int r = 0; r < 4; ++r){
        ep0[r] = eb[(size_t)r*NST + n0];
        ep1[r] = (two && n1 < 200) ? (u32)eb[(size_t)r*NST + n1] : 0u;
      }
    }

    // ---- read ah (hb[pb] stable since GATES of prev step) ----
    bf16x8 ah[7];
    #pragma unroll
    for (int kt = 0; kt < 7; ++kt)
      ah[kt] = *(const bf16x8*)(&hb[pb][nl][kt*32 + q*8]);

    // ---- LAT: x = relu(Wcomp.zq + Wla_a.a + b) ----
    {
      bf16x8 aL[8];
      #pragma unroll
      for (int kt = 0; kt < 7; ++kt)
        aL[kt] = *(const bf16x8*)(&zqb[nl][kt*32 + q*8]);
      aL[7] = *(const bf16x8*)(&xs[nl][q*8]);

      f32x4 L0 = {0.f,0.f,0.f,0.f}, L1 = {0.f,0.f,0.f,0.f};
      if (two) { LOAD8(b1, wCLA, wave + 8); }
      LOAD7(b2, wIH, wave*3);
      SB();
      CHAIN8(L0, aL, b0);                            // b0 = CLA(wave)
      LOAD7(b0, wHH, wave*3);
      SB();
      if (two) { CHAIN8(L1, aL, b1); }

      #pragma unroll
      for (int c = 0; c < 2; ++c){
        if (c < cmax){
          const f32x4& L = c ? L1 : L0;
          const int n = (wave + 8*c)*16 + nl;
          const float lb = (t == 0) ? latb_r[c] : latb2_r[c];
          if (n < 200){
            #pragma unroll
            for (int r = 0; r < 4; ++r)
              xb[q*4 + r][n] = f2bf(fmaxf(L[r] + lb, 0.f));
          }
        }
      }
    }
    BAR();                                           // B1

    // ---- GATES: ring with pinned 2-unit lookahead ----
    // entry per c: b2 = IH(gu), b0 = HH(gu), b1 free
    {
      bf16x8 ax[7];
      #pragma unroll
      for (int kt = 0; kt < 7; ++kt)
        ax[kt] = *(const bf16x8*)(&xb[nl][kt*32 + q*8]);
      if (uth && t + 1 < Tq) u_reg = u[((size_t)(row0 + ur)*Tq + (t + 1))*NACT + uk];

      float* os = out_states + ((size_t)t*Bq + row0)*NST;

      #pragma unroll
      for (int c = 0; c < 2; ++c){
        if (c < cmax){
          const int g  = wave + 8*c;
          const int gu = g*3;
          const bool last = (c + 1 == cmax);
          f32x4 a0  = {0.f,0.f,0.f,0.f};             // r gate (ih+hh merged)
          f32x4 a1  = {0.f,0.f,0.f,0.f};             // z gate (ih+hh merged)
          f32x4 a2i = {0.f,0.f,0.f,0.f};             // n gate ih
          f32x4 a2h = {0.f,0.f,0.f,0.f};             // n gate hh

          LOAD7(b1, wIH, gu + 1);  SB();  CHAIN7(a0, ax, b2);
          LOAD7(b2, wHH, gu + 1);  SB();  CHAIN7(a0, ah, b0);
          LOAD7(b0, wIH, gu + 2);  SB();  CHAIN7(a1, ax, b1);
          LOAD7(b1, wHH, gu + 2);  SB();  CHAIN7(a1, ah, b2);
          if (last) { LOAD7(b2, wP1, wave); }
          else      { LOAD7(b2, wIH, (wave + 8)*3); }
          SB();  CHAIN7(a2i, ax, b0);
          if (last) { LOAD8(b0, wCLA, wave); }       // next-step CLA(wave)
          else      { LOAD7(b0, wHH, (wave + 8)*3); }
          SB();  CHAIN7(a2h, ah, b1);

          const int n = g*16 + nl;
          if (n < 200){
            #pragma unroll
            for (int r = 0; r < 4; ++r){
              const int m = q*4 + r;
              float rg = fsigm(a0[r] + brz_r[c][0]);
              float zg = fsigm(a1[r] + brz_r[c][1]);
              float ng = ftanh(a2i[r] + bin_r[c] + rg*(a2h[r] + bhn_r[c]));
              float hn = (1.f - zg)*ng + zg*hreg[c][r];
              hreg[c][r] = hn;
              hb[pb ^ 1][m][n] = f2bf(hn);
              os[(size_t)m*NST + n] = hn;
            }
          }
        }
      }
    }
    BAR();                                           // B2

    // ---- P1: zq = relu(h_new @ Wp1^T + Epost) ----
    // entry: b2 = P1(wave), b0 = CLA(wave) [kept for next LAT], b1 free
    {
      bf16x8 ah2[7];
      #pragma unroll
      for (int kt = 0; kt < 7; ++kt)
        ah2[kt] = *(const bf16x8*)(&hb[pb ^ 1][nl][kt*32 + q*8]);
      f32x4 aP0 = {0.f,0.f,0.f,0.f}, aP1 = {0.f,0.f,0.f,0.f};
      if (two) { LOAD7(b1, wP1, wave + 8); }
      SB();
      CHAIN7(aP0, ah2, b2);
      SB();
      if (two) { CHAIN7(aP1, ah2, b1); }
      {
        const int n0 = wave*16 + nl;
        #pragma unroll
        for (int r = 0; r < 4; ++r)
          zqb[q*4 + r][n0] = f2bf(fmaxf(aP0[r] + bf2f((u16)ep0[r]), 0.f));
        if (two){
          const int n1 = n0 + 128;
          if (n1 < 200){
            #pragma unroll
            for (int r = 0; r < 4; ++r)
              zqb[q*4 + r][n1] = f2bf(fmaxf(aP1[r] + bf2f((u16)ep1[r]), 0.f));
          }
        }
      }
    }
    // loop back; B0 of next iteration synchronizes. Invariant: b0 = CLA(wave).
  }
}

// ---------------- kernel 4: prior branch + all four heads, MFMA end-to-end ----------------
__global__ __launch_bounds__(256) void phasec_kernel(
    const float* __restrict__ states,
    const u16* __restrict__ Epost,
    const u16* __restrict__ wbuf,
    const float* __restrict__ prior1_b,
    const float* __restrict__ prior_m_b,
    const float* __restrict__ prior_s_b,
    const float* __restrict__ post_m_b,
    const float* __restrict__ post_s_b,
    float* __restrict__ pm, float* __restrict__ ps,
    float* __restrict__ qm, float* __restrict__ qs)
{
  __shared__ __align__(16) u16 stb[32][232];      // states bf16, K-pad
  __shared__ __align__(16) u16 zpb[32][232];      // zp bf16 (cols 200+ zero)
  __shared__ __align__(16) u16 zq2[32][232];      // zq bf16 (cols 200+ zero)
  const int tid = threadIdx.x, wave = tid >> 6, lane = tid & 63, nl = lane & 15, q = lane >> 4;
  const size_t m0 = (size_t)blockIdx.x * 32;
  const u16* wP1  = wbuf + (size_t)T_P1 * 512;
  const u16* wPR1 = wbuf + (size_t)T_PR1 * 512;
  const u16* wHD  = wbuf + (size_t)T_HD * 512;

  for (int i = tid; i < 32*232; i += 256){
    ((u16*)zpb)[i] = 0; ((u16*)zq2)[i] = 0;
  }
  for (int i = tid; i < 32*200; i += 256){
    int r = i / 200, c = i - r*200;
    stb[r][c] = f2bf(states[(m0 + r)*NST + c]);
  }
  for (int i = tid; i < 32*32; i += 256){
    int r = i >> 5, c = i & 31;
    stb[r][200 + c] = 0;
  }
  __syncthreads();

  // phase 1: zp = relu(h@Wpr1^T + b), zq = relu(h@Wp1^T + Epost) — bf16 out
  {
    const int rowb = (wave & 1) * 16;
    const bool doZQ = (wave >= 2);
    const u16* wmat = doZQ ? wP1 : wPR1;
    bf16x8 a7[7];
    #pragma unroll
    for (int kt = 0; kt < 7; ++kt)
      a7[kt] = *(const bf16x8*)(&stb[rowb + nl][kt*32 + q*8]);
    for (int nt = 0; nt < 13; ++nt){
      f32x4 a = {0.f, 0.f, 0.f, 0.f};
      #pragma unroll
      for (int kt = 0; kt < 7; ++kt){
        bf16x8 b = *(const bf16x8*)(wmat + (((size_t)(nt*7 + kt)) << 9) + lane*8);
        a = __builtin_amdgcn_mfma_f32_16x16x32_bf16(a7[kt], b, a, 0, 0, 0);
      }
      int n = nt*16 + nl;
      if (n < 200){
        #pragma unroll
        for (int r = 0; r < 4; ++r){
          int m = rowb + q*4 + r;
          if (doZQ){
            float v = a[r] + bf2f(Epost[(m0 + m)*NST + n]);
            zq2[m][n] = f2bf(fmaxf(v, 0.f));
          } else {
            float v = a[r] + prior1_b[n];
            zpb[m][n] = f2bf(fmaxf(v, 0.f));
          }
        }
      }
    }
  }
  __syncthreads();

  // phase 2: heads via MFMA. wave = head (0=pm, 1=ps, 2=qm, 3=qs)
  {
    const int hd = wave;
    const bool isStd = (hd & 1);
    const float* hb_p = hd == 0 ? prior_m_b : hd == 1 ? prior_s_b :
                        hd == 2 ? post_m_b  : post_s_b;
    float* o = hd == 0 ? pm : hd == 1 ? ps : hd == 2 ? qm : qs;
    const u16 (*src)[232] = (hd < 2) ? zpb : zq2;

    #pragma unroll
    for (int rb = 0; rb < 2; ++rb){
      const int rowb = rb * 16;
      bf16x8 a7[7];
      #pragma unroll
      for (int kt = 0; kt < 7; ++kt)
        a7[kt] = *(const bf16x8*)(&src[rowb + nl][kt*32 + q*8]);
      #pragma unroll
      for (int nt = 0; nt < 2; ++nt){
        f32x4 a = {0.f, 0.f, 0.f, 0.f};
        #pragma unroll
        for (int kt = 0; kt < 7; ++kt){
          bf16x8 b = *(const bf16x8*)(wHD + (((size_t)((hd*2 + nt)*7 + kt)) << 9) + lane*8);
          a = __builtin_amdgcn_mfma_f32_16x16x32_bf16(a7[kt], b, a, 0, 0, 0);
        }
        int n = nt*16 + nl;
        if (n < 30){
          float bb = hb_p[n];
          #pragma unroll
          for (int r = 0; r < 4; ++r){
            int m = rowb + q*4 + r;
            float v = a[r] + bb;
            if (isStd) v = stdf_(v);
            o[(m0 + m)*NLAT + n] = v;
          }
        }
      }
    }
  }
}

// ---------------- launcher ----------------
extern "C" void kernel_launch(void* const* d_in, const int* in_sizes, int n_in,
                              void* d_out, int out_size, void* d_ws, size_t ws_size,
                              hipStream_t stream)
{
  const float* e         = (const float*)d_in[0];
  const float* u         = (const float*)d_in[1];
  const float* lat_act_W = (const float*)d_in[2];
  const float* lat_act_b = (const float*)d_in[3];
  const float* gru_Wih   = (const float*)d_in[4];
  const float* gru_Whh   = (const float*)d_in[5];
  const float* gru_bih   = (const float*)d_in[6];
  const float* gru_bhh   = (const float*)d_in[7];
  const float* prior1_W  = (const float*)d_in[8];
  const float* prior1_b  = (const float*)d_in[9];
  const float* prior_m_W = (const float*)d_in[10];
  const float* prior_m_b = (const float*)d_in[11];
  const float* prior_s_W = (const float*)d_in[12];
  const float* prior_s_b = (const float*)d_in[13];
  const float* post1_W   = (const float*)d_in[14];
  const float* post1_b   = (const float*)d_in[15];
  const float* post_m_W  = (const float*)d_in[16];
  const float* post_m_b  = (const float*)d_in[17];
  const float* post_s_W  = (const float*)d_in[18];
  const float* post_s_b  = (const float*)d_in[19];

  float* out    = (float*)d_out;
  float* states = out;                       // [100][512][200]
  float* pm     = out + 10240000;
  float* ps     = out + 11776000;
  float* qm     = out + 13312000;
  float* qs     = out + 14848000;

  u16* Epost = (u16*)d_ws;                               // 10,240,000 bf16 = 20.48 MB
  u16* wbuf  = (u16*)((char*)d_ws + 20480000);           // 1.38 MB packed weights

  hipLaunchKernelGGL(prep2, dim3((NFRAG + 255) / 256), dim3(256), 0, stream,
                     lat_act_W, gru_Wih, gru_Whh, post1_W, post_m_W, prior1_W,
                     prior_m_W, prior_s_W, post_s_W, wbuf);

  hipLaunchKernelGGL(epost_kernel, dim3(800), dim3(256), 0, stream,
                     e, post1_b, wbuf, Epost);

  hipLaunchKernelGGL(core_kernel, dim3(32), dim3(512), 0, stream,
                     u, lat_act_b, lat_act_W, post_m_b, gru_bih, gru_bhh,
                     wbuf, Epost, states);

  hipLaunchKernelGGL(phasec_kernel, dim3(1600), dim3(256), 0, stream,
                     states, Epost, wbuf, prior1_b,
                     prior_m_b, prior_s_b, post_m_b, post_s_b,
                     pm, ps, qm, qs);
}